// Round 19
// baseline (384.396 us; speedup 1.0000x reference)
//
#include <hip/hip_runtime.h>
#include <hip/hip_bf16.h>

// NoisyActLin: y = fakequant(x) @ fakequant(W).T + bias
// x: [4,2048,2048] f32 -> M=8192, K=2048 ; W: [8192,2048] f32 -> N=8192
// out: [8192, 8192] f32
//
// R19: fragment-major LDS + 32x32x16 f16 MFMA, on R18's compiler-scheduled
// fat-tile structure.
// - Fragment-major: each MFMA fragment's 16B/lane lives at slot*1024+lane*16
//   (pre-permuted global source, linear gload_lds dest). ds_read = base +
//   lane*16 + imm offset -> conflict-free by construction, near-zero VALU
//   address math (R18 VALUBusy was 22%).
// - 32x32x16 f16: same LDS traffic, +11% MFMA rate (2178 vs 1955 TF ubench),
//   half the MFMA instruction count. A/B layout: lane l holds [l&31][(l>>5)*8+j]
//   (analog of verified 16x16x32); C/D col=lane&31, row=(reg&3)+8(reg>>2)+
//   4(lane>>5) [m74/m101].
// - Keeps: R13 XCD map (FETCH 197MB), R9 wait discipline (own-wave vmcnt(0)
//   BEFORE barrier), fused quant kernel.

using f16x8  = __attribute__((ext_vector_type(8))) _Float16;
using f32x16 = __attribute__((ext_vector_type(16))) float;

#define AS1 __attribute__((address_space(1)))
#define AS3 __attribute__((address_space(3)))

static __device__ __forceinline__ void gload_lds16(const void* g, void* l) {
    __builtin_amdgcn_global_load_lds((const AS1 void*)g, (AS3 void*)l, 16, 0, 0);
}

// ---------------- fused fake-quant: x elementwise + W per-row ----------------
__global__ __launch_bounds__(256) void quant_kernel(
    const float* __restrict__ X,
    const float* __restrict__ las, const float* __restrict__ laq,
    const float* __restrict__ ab,
    const float* __restrict__ W, const float* __restrict__ lws,
    _Float16* __restrict__ Xq, _Float16* __restrict__ Wq) {
    constexpr int K = 2048;
    __shared__ float smn[4], smx[4];
    const int t = threadIdx.x;

    if (blockIdx.x < 8192) {
        const float ls = las[0], lq = laq[0];
        const float s = exp2f(ls);
        const float rs = exp2f(-ls);
        const float q = exp2f(lq);
        const float zp = rintf(ab[0] * rs * 2.0f) * 0.5f * s;  // ACT_GUARD=2
        const float lo = zp;
        const float hi = (zp + q) - s;

        const size_t base = ((size_t)blockIdx.x * 256 + t) * 8;
        float4 v0 = *(const float4*)&X[base];
        float4 v1 = *(const float4*)&X[base + 4];
        float vals[8] = {v0.x, v0.y, v0.z, v0.w, v1.x, v1.y, v1.z, v1.w};

        f16x8 out;
#pragma unroll
        for (int i = 0; i < 8; ++i) {
            float c = fminf(fmaxf(vals[i], lo), hi);
            float qx = rintf((c - zp) * rs);
            out[i] = (_Float16)(qx * s + zp);
        }
        *(f16x8*)&Xq[base] = out;
    } else {
        const int row = blockIdx.x - 8192;
        const float* w = W + (size_t)row * K;

        float4 v0 = ((const float4*)w)[t * 2];
        float4 v1 = ((const float4*)w)[t * 2 + 1];
        float vals[8] = {v0.x, v0.y, v0.z, v0.w, v1.x, v1.y, v1.z, v1.w};

        float mn = vals[0], mx = vals[0];
#pragma unroll
        for (int i = 1; i < 8; ++i) {
            mn = fminf(mn, vals[i]);
            mx = fmaxf(mx, vals[i]);
        }
#pragma unroll
        for (int off = 32; off >= 1; off >>= 1) {
            mn = fminf(mn, __shfl_xor(mn, off));
            mx = fmaxf(mx, __shfl_xor(mx, off));
        }
        if ((t & 63) == 0) { smn[t >> 6] = mn; smx[t >> 6] = mx; }
        __syncthreads();
        mn = fminf(fminf(smn[0], smn[1]), fminf(smn[2], smn[3]));
        mx = fmaxf(fmaxf(smx[0], smx[1]), fmaxf(smx[2], smx[3]));

        const float l = lws[row];
        const float ws = exp2f(l);
        const float rs = exp2f(-l);
        const float qwmin = rintf(mn * rs * 2.0f) * 0.5f * ws;  // WGT_GUARD=2
        const float qwmax = rintf(mx * rs * 2.0f) * 0.5f * ws;

        f16x8 out;
#pragma unroll
        for (int i = 0; i < 8; ++i) {
            float c = fminf(fmaxf(vals[i], qwmin), qwmax);
            float qw = rintf((c - qwmin) * rs);
            out[i] = (_Float16)(qw * ws + qwmin);
        }
        *(f16x8*)&Wq[(size_t)row * K + (size_t)t * 8] = out;
    }
}

// ---------------- GEMM: C[M][N] = A[M][K] * B[N][K]^T + bias ----------------
// Block 256x256, 8 waves (wr=wid>>2 in {0,1}, wc=wid&3 in {0..3}),
// per-wave 128x64 via 32x32x16 MFMA: m in 0..3, n in 0..1, ks in 0..3.
// LDS 128KB, fragment-major:
//   A: smem + db*32768 + slot*1024 + lane*16, slot = wr*16 + m*4 + ks
//   B: smem + 65536 + db*32768 + slot*1024 + lane*16, slot = (wc*2+n)*4 + ks
// Fragment element for lane l: row/col = l&31, k = (l>>5)*8 + 0..7.
// Staging: thread t stages chunks c = t + i*512 (i=0..3) for A and B;
// global source offset precomputed from (slot,lane) decode of c (rule 21:
// permute the SOURCE, keep LDS dest linear).
// Per K-tile (fat phase, compiler-scheduled waits):
//   STAGET(db^1, kt+1) ; 24 ds_read_b128 (ks-grouped) ; 32 MFMA ;
//   vmcnt(0)"memory" ; s_barrier          (R9 landing rule; WAR as R18)
__global__ __launch_bounds__(512, 2) void gemm_kernel(
    const _Float16* __restrict__ A, const _Float16* __restrict__ B,
    const float* __restrict__ bias, float* __restrict__ C) {
    constexpr int N = 8192, K = 2048;
    constexpr int KT = K / 64;          // 32 K-tiles
    __shared__ char smem[131072];       // A: 0..64K (2 dbufs), B: 64K..128K

    // L2/L3-aware mapping (R13): XCD x owns A-band [4x,4x+4); bm fastest.
    const int bid = blockIdx.x;
    const int j = bid >> 3;
    const int bm = (bid & 7) * 4 + (j & 3);
    const int bn = j >> 2;

    const int t = threadIdx.x;
    const int lane = t & 63;
    const int wid = t >> 6;
    const int wr = wid >> 2;            // 0..1 (M half)
    const int wc = wid & 3;             // 0..3 (N quarter)
    const int l31 = lane & 31;
    const int lh = lane >> 5;           // 0..1 (k-half of fragment)

    const _Float16* Agb = A + (size_t)bm * 256 * K;
    const _Float16* Bgb = B + (size_t)bn * 256 * K;

    // ---- staging source offsets (fragment-major permutation) ----
    int goffA[4], goffB[4];
#pragma unroll
    for (int i = 0; i < 4; ++i) {
        const int c = t + i * 512;      // chunk id, 0..2047
        const int s = c >> 6;           // slot 0..31
        const int ln = c & 63;
        const int kk = (s & 3) * 16 + (ln >> 5) * 8;
        const int rowA = (s >> 4) * 128 + ((s >> 2) & 3) * 32 + (ln & 31);
        goffA[i] = rowA * K + kk;
        const int rowB = (s >> 3) * 64 + ((s >> 2) & 1) * 32 + (ln & 31);
        goffB[i] = rowB * K + kk;
    }

    f32x16 acc[4][2] = {};
    f16x8 fa[4][4], fb[2][4];

#define STAGET(DBS, KS) do {                                                   \
        _Pragma("unroll")                                                      \
        for (int _i = 0; _i < 4; ++_i)                                         \
            gload_lds16(Agb + goffA[_i] + (KS) * 64,                           \
                        smem + (DBS) * 32768 + (t + _i * 512) * 16);           \
        _Pragma("unroll")                                                      \
        for (int _i = 0; _i < 4; ++_i)                                         \
            gload_lds16(Bgb + goffB[_i] + (KS) * 64,                           \
                        smem + 65536 + (DBS) * 32768 + (t + _i * 512) * 16);   \
    } while (0)

    // ---- prologue: stage tile 0 into db0; drain BEFORE barrier ----
    STAGET(0, 0);
    asm volatile("s_waitcnt vmcnt(0)" ::: "memory");
    __builtin_amdgcn_s_barrier();

    for (int kt = 0; kt < KT; ++kt) {
        const int db = kt & 1;
        const int nx = (kt + 1 < KT) ? kt + 1 : KT - 1;

        STAGET(db ^ 1, nx);              // 8 loads for tile kt+1

        // 24 ds_read_b128 (ks-grouped; compiler inserts counted lgkm)
        const char* baseA = smem + db * 32768 + wr * 16384 + lane * 16;
        const char* baseB = smem + 65536 + db * 32768 + wc * 8192 + lane * 16;
#pragma unroll
        for (int ks = 0; ks < 4; ++ks) {
#pragma unroll
            for (int m = 0; m < 4; ++m)
                fa[m][ks] = *(const f16x8*)(baseA + (m * 4 + ks) * 1024);
#pragma unroll
            for (int n = 0; n < 2; ++n)
                fb[n][ks] = *(const f16x8*)(baseB + (n * 4 + ks) * 1024);
        }

        // 32 MFMA, ks-outer (acc reuse distance 8)
#pragma unroll
        for (int ks = 0; ks < 4; ++ks)
#pragma unroll
            for (int m = 0; m < 4; ++m)
#pragma unroll
                for (int n = 0; n < 2; ++n)
                    acc[m][n] = __builtin_amdgcn_mfma_f32_32x32x16_f16(
                        fa[m][ks], fb[n][ks], acc[m][n], 0, 0, 0);

        asm volatile("s_waitcnt vmcnt(0)" ::: "memory");  // own stages landed
        __builtin_amdgcn_s_barrier();    // => all waves' stages landed
    }
#undef STAGET

    // ---- epilogue: 32x32 C/D: col=lane&31, row=(reg&3)+8*(reg>>2)+4*lh ----
#pragma unroll
    for (int m = 0; m < 4; ++m) {
        const int row0 = bm * 256 + wr * 128 + m * 32 + 4 * lh;
#pragma unroll
        for (int n = 0; n < 2; ++n) {
            const int col = bn * 256 + wc * 64 + n * 32 + l31;
            const float bv = bias[col];
#pragma unroll
            for (int r = 0; r < 16; ++r) {
                const int row = row0 + (r & 3) + 8 * (r >> 2);
                C[(size_t)row * N + col] = acc[m][n][r] + bv;
            }
        }
    }
}

extern "C" void kernel_launch(void* const* d_in, const int* in_sizes, int n_in,
                              void* d_out, int out_size, void* d_ws, size_t ws_size,
                              hipStream_t stream) {
    const float* x    = (const float*)d_in[0];   // [4,2048,2048]
    const float* w    = (const float*)d_in[1];   // [8192,2048]
    const float* bias = (const float*)d_in[2];   // [8192]
    const float* las  = (const float*)d_in[3];   // log_act_s [1]
    const float* laq  = (const float*)d_in[4];   // log_act_q [1]
    const float* ab   = (const float*)d_in[5];   // act_b [1]
    const float* lws  = (const float*)d_in[6];   // log_wght_s [8192]
    float* out = (float*)d_out;

    constexpr size_t MK = (size_t)8192 * 2048;
    _Float16* xq = (_Float16*)d_ws;
    _Float16* wq = (_Float16*)((char*)d_ws + MK * sizeof(_Float16));

    quant_kernel<<<16384, 256, 0, stream>>>(x, las, laq, ab, w, lws, xq, wq);
    gemm_kernel<<<1024, 512, 0, stream>>>(xq, wq, bias, out);
}

// Round 20
// 277.406 us; speedup vs baseline: 1.3857x; 1.3857x over previous
//
#include <hip/hip_runtime.h>
#include <hip/hip_bf16.h>

// NoisyActLin: y = fakequant(x) @ fakequant(W).T + bias
// x: [4,2048,2048] f32 -> M=8192, K=2048 ; W: [8192,2048] f32 -> N=8192
// out: [8192, 8192] f32
//
// R20 = R18 (best: 250us GEMM, compiler-scheduled waits) + chunked tile body
// separated ONLY by sched_barrier(0) (compile-time fence; no hidden waitcnt
// drains, unlike "memory"-clobbered asm — R17 lesson).
// FIFO model (R19 post-mortem): R18 issues all 24 ds_reads per wave up
// front -> 192 block-wide reads (~2300cyc port) queue BEFORE any MFMA.
// Chunking to {6 rd, 8-16 mm} x5 interleaves: wave w's reads drain while
// other waves MFMA -> port head ~575cyc, rest hides under the MFMA stream.
// Keeps: T2 swizzle (0 conflicts), R13 XCD map (FETCH 197MB), R9 rule
// (own-wave vmcnt(0) BEFORE barrier), fused quant.

using f16x8 = __attribute__((ext_vector_type(8))) _Float16;
using f32x4 = __attribute__((ext_vector_type(4))) float;

#define AS1 __attribute__((address_space(1)))
#define AS3 __attribute__((address_space(3)))

static __device__ __forceinline__ void gload_lds16(const void* g, void* l) {
    __builtin_amdgcn_global_load_lds((const AS1 void*)g, (AS3 void*)l, 16, 0, 0);
}

// ---------------- fused fake-quant: x elementwise + W per-row ----------------
__global__ __launch_bounds__(256) void quant_kernel(
    const float* __restrict__ X,
    const float* __restrict__ las, const float* __restrict__ laq,
    const float* __restrict__ ab,
    const float* __restrict__ W, const float* __restrict__ lws,
    _Float16* __restrict__ Xq, _Float16* __restrict__ Wq) {
    constexpr int K = 2048;
    __shared__ float smn[4], smx[4];
    const int t = threadIdx.x;

    if (blockIdx.x < 8192) {
        const float ls = las[0], lq = laq[0];
        const float s = exp2f(ls);
        const float rs = exp2f(-ls);
        const float q = exp2f(lq);
        const float zp = rintf(ab[0] * rs * 2.0f) * 0.5f * s;  // ACT_GUARD=2
        const float lo = zp;
        const float hi = (zp + q) - s;

        const size_t base = ((size_t)blockIdx.x * 256 + t) * 8;
        float4 v0 = *(const float4*)&X[base];
        float4 v1 = *(const float4*)&X[base + 4];
        float vals[8] = {v0.x, v0.y, v0.z, v0.w, v1.x, v1.y, v1.z, v1.w};

        f16x8 out;
#pragma unroll
        for (int i = 0; i < 8; ++i) {
            float c = fminf(fmaxf(vals[i], lo), hi);
            float qx = rintf((c - zp) * rs);
            out[i] = (_Float16)(qx * s + zp);
        }
        *(f16x8*)&Xq[base] = out;
    } else {
        const int row = blockIdx.x - 8192;
        const float* w = W + (size_t)row * K;

        float4 v0 = ((const float4*)w)[t * 2];
        float4 v1 = ((const float4*)w)[t * 2 + 1];
        float vals[8] = {v0.x, v0.y, v0.z, v0.w, v1.x, v1.y, v1.z, v1.w};

        float mn = vals[0], mx = vals[0];
#pragma unroll
        for (int i = 1; i < 8; ++i) {
            mn = fminf(mn, vals[i]);
            mx = fmaxf(mx, vals[i]);
        }
#pragma unroll
        for (int off = 32; off >= 1; off >>= 1) {
            mn = fminf(mn, __shfl_xor(mn, off));
            mx = fmaxf(mx, __shfl_xor(mx, off));
        }
        if ((t & 63) == 0) { smn[t >> 6] = mn; smx[t >> 6] = mx; }
        __syncthreads();
        mn = fminf(fminf(smn[0], smn[1]), fminf(smn[2], smn[3]));
        mx = fmaxf(fmaxf(smx[0], smx[1]), fmaxf(smx[2], smx[3]));

        const float l = lws[row];
        const float ws = exp2f(l);
        const float rs = exp2f(-l);
        const float qwmin = rintf(mn * rs * 2.0f) * 0.5f * ws;  // WGT_GUARD=2
        const float qwmax = rintf(mx * rs * 2.0f) * 0.5f * ws;

        f16x8 out;
#pragma unroll
        for (int i = 0; i < 8; ++i) {
            float c = fminf(fmaxf(vals[i], qwmin), qwmax);
            float qw = rintf((c - qwmin) * rs);
            out[i] = (_Float16)(qw * ws + qwmin);
        }
        *(f16x8*)&Wq[(size_t)row * K + (size_t)t * 8] = out;
    }
}

// ---------------- GEMM: C[M][N] = A[M][K] * B[N][K]^T + bias ----------------
// == R18 structure; tile body split into 5 sched_barrier(0)-fenced chunks ==
// LDS: A [db2][half2][128][64] f16 at 0 (64KB), B same at +65536 (128KB).
// 8 waves (2Mx4N), 128x64/wave. Per K-tile:
//   STAGET(db^1, kt+1)                                   8 gload_lds
//   c0: rd{A0-3k0,B0-1k0}  -> mm (m0-3)x(n0-1) k0        6 rd,  8 mm
//   c1: rd{A4-7k0,B2-3k0}  -> mm (m4-7)x(n0-1) k0,
//                             (m0-3)x(n2-3) k0           6 rd, 16 mm
//   c2: rd{A0-3k1,B0-1k1}  -> mm (m4-7)x(n2-3) k0,
//                             (m0-3)x(n0-1) k1           6 rd, 16 mm
//   c3: rd{A4-7k1,B2-3k1}  -> mm (m0-3)x(n2-3) k1,
//                             (m4-7)x(n0-1) k1           6 rd, 16 mm
//   c4:                       mm (m4-7)x(n2-3) k1               8 mm
//   vmcnt(0)"memory" ; s_barrier      (R9 landing rule; WAR as R18 —
//   all tile-kt reads retire via MFMA data deps before the end barrier)
__global__ __launch_bounds__(512, 2) void gemm_kernel(
    const _Float16* __restrict__ A, const _Float16* __restrict__ B,
    const float* __restrict__ bias, float* __restrict__ C) {
    constexpr int N = 8192, K = 2048;
    constexpr int KT = K / 64;          // 32 K-tiles
    __shared__ char smem[131072];       // A: 0..64K, B: 64K..128K

    // L2/L3-aware mapping (R13): XCD x owns A-band [4x,4x+4); bm fastest.
    const int bid = blockIdx.x;
    const int j = bid >> 3;
    const int bm = (bid & 7) * 4 + (j & 3);
    const int bn = j >> 2;

    const int t = threadIdx.x;
    const int lane = t & 63;
    const int wid = t >> 6;
    const int wr = wid >> 2;            // 0..1 (M half)
    const int wc = wid & 3;             // 0..3 (N quarter)
    const int l15 = lane & 15;
    const int lq = lane >> 4;

    // staging: half-tile [128][64] f16 = 16KB, linear dest, pre-swizzled
    // source. T2 swizzle: byte ^= (row&7)<<4 (verified 0 conflicts).
    const int d0 = t * 16, d1 = d0 + 8192;
    const int r0 = d0 >> 7, c0s = (((d0 & 127) ^ (((d0 >> 7) & 7) << 4)) >> 1);
    const int r1 = d1 >> 7, c1s = (((d1 & 127) ^ (((d1 >> 7) & 7) << 4)) >> 1);
    const _Float16* Agb = A + (size_t)bm * 256 * K;
    const _Float16* Bgb = B + (size_t)bn * 256 * K;

    // read-side swizzled k-col byte offsets (frag row&7 == l15&7)
    const int cp0 = (lq * 16) ^ ((l15 & 7) << 4);
    const int cp1 = cp0 ^ 64;           // second K-half (bit6 XOR)

    f32x4 acc[8][4] = {};
    f16x8 fA[8][2], fB[4][2];

#define STAGEH(GB, RO, DBS, H, KS) do {                                        \
        const _Float16* _g = (GB) + (size_t)((H) * 128) * K + (size_t)(KS) * 64;\
        char* _l = smem + (RO) + ((DBS) * 2 + (H)) * 16384;                    \
        gload_lds16(_g + (size_t)r0 * K + c0s, _l + d0);                       \
        gload_lds16(_g + (size_t)r1 * K + c1s, _l + d1);                       \
    } while (0)

#define STAGET(DBS, KS) do {                                                   \
        STAGEH(Agb, 0,     DBS, 0, KS);                                        \
        STAGEH(Agb, 0,     DBS, 1, KS);                                        \
        STAGEH(Bgb, 65536, DBS, 0, KS);                                        \
        STAGEH(Bgb, 65536, DBS, 1, KS);                                        \
    } while (0)

#define RDA(M, KI) fA[M][KI] = *(const f16x8*)(_a + (M) * 2048 + ((KI) ? cp1 : cp0))
#define RDB(Nn, KI) fB[Nn][KI] = *(const f16x8*)(_b + (Nn) * 2048 + ((KI) ? cp1 : cp0))
#define MM(M, Nn, KI)                                                          \
    acc[M][Nn] = __builtin_amdgcn_mfma_f32_16x16x32_f16(                       \
        fA[M][KI], fB[Nn][KI], acc[M][Nn], 0, 0, 0)
#define SB() __builtin_amdgcn_sched_barrier(0)

    // ---- prologue: stage tile 0 into db0; drain BEFORE barrier ----
    STAGET(0, 0);
    asm volatile("s_waitcnt vmcnt(0)" ::: "memory");
    __builtin_amdgcn_s_barrier();

    for (int kt = 0; kt < KT; ++kt) {
        const int db = kt & 1;
        const int nx = (kt + 1 < KT) ? kt + 1 : KT - 1;

        STAGET(db ^ 1, nx);              // 8 loads for tile kt+1

        const char* _a = smem + (db * 2 + wr) * 16384 + l15 * 128;
        const char* _b = smem + 65536 + (db * 2 + (wc >> 1)) * 16384 +
                         (wc & 1) * 8192 + l15 * 128;

        // ---- c0: 6 rd -> 8 mm ----
        RDA(0,0); RDA(1,0); RDA(2,0); RDA(3,0); RDB(0,0); RDB(1,0);
        SB();
        MM(0,0,0); MM(0,1,0); MM(1,0,0); MM(1,1,0);
        MM(2,0,0); MM(2,1,0); MM(3,0,0); MM(3,1,0);
        SB();
        // ---- c1: 6 rd -> 16 mm ----
        RDA(4,0); RDA(5,0); RDA(6,0); RDA(7,0); RDB(2,0); RDB(3,0);
        SB();
        MM(4,0,0); MM(4,1,0); MM(5,0,0); MM(5,1,0);
        MM(6,0,0); MM(6,1,0); MM(7,0,0); MM(7,1,0);
        MM(0,2,0); MM(0,3,0); MM(1,2,0); MM(1,3,0);
        MM(2,2,0); MM(2,3,0); MM(3,2,0); MM(3,3,0);
        SB();
        // ---- c2: 6 rd -> 16 mm ----
        RDA(0,1); RDA(1,1); RDA(2,1); RDA(3,1); RDB(0,1); RDB(1,1);
        SB();
        MM(4,2,0); MM(4,3,0); MM(5,2,0); MM(5,3,0);
        MM(6,2,0); MM(6,3,0); MM(7,2,0); MM(7,3,0);
        MM(0,0,1); MM(0,1,1); MM(1,0,1); MM(1,1,1);
        MM(2,0,1); MM(2,1,1); MM(3,0,1); MM(3,1,1);
        SB();
        // ---- c3: 6 rd -> 16 mm ----
        RDA(4,1); RDA(5,1); RDA(6,1); RDA(7,1); RDB(2,1); RDB(3,1);
        SB();
        MM(0,2,1); MM(0,3,1); MM(1,2,1); MM(1,3,1);
        MM(2,2,1); MM(2,3,1); MM(3,2,1); MM(3,3,1);
        MM(4,0,1); MM(4,1,1); MM(5,0,1); MM(5,1,1);
        MM(6,0,1); MM(6,1,1); MM(7,0,1); MM(7,1,1);
        SB();
        // ---- c4: 8 mm tail ----
        MM(4,2,1); MM(4,3,1); MM(5,2,1); MM(5,3,1);
        MM(6,2,1); MM(6,3,1); MM(7,2,1); MM(7,3,1);

        asm volatile("s_waitcnt vmcnt(0)" ::: "memory");  // own stages landed
        __builtin_amdgcn_s_barrier();    // => all waves' stages landed
    }
#undef STAGEH
#undef STAGET
#undef RDA
#undef RDB
#undef MM
#undef SB

    // ---- epilogue: C/D mapping col=lane&15, row=(lane>>4)*4+reg ----
#pragma unroll
    for (int m = 0; m < 8; ++m) {
        const int row = bm * 256 + wr * 128 + m * 16 + lq * 4;
#pragma unroll
        for (int n = 0; n < 4; ++n) {
            const int col = bn * 256 + wc * 64 + n * 16 + l15;
            const float bv = bias[col];
#pragma unroll
            for (int r = 0; r < 4; ++r) {
                C[(size_t)(row + r) * N + col] = acc[m][n][r] + bv;
            }
        }
    }
}

extern "C" void kernel_launch(void* const* d_in, const int* in_sizes, int n_in,
                              void* d_out, int out_size, void* d_ws, size_t ws_size,
                              hipStream_t stream) {
    const float* x    = (const float*)d_in[0];   // [4,2048,2048]
    const float* w    = (const float*)d_in[1];   // [8192,2048]
    const float* bias = (const float*)d_in[2];   // [8192]
    const float* las  = (const float*)d_in[3];   // log_act_s [1]
    const float* laq  = (const float*)d_in[4];   // log_act_q [1]
    const float* ab   = (const float*)d_in[5];   // act_b [1]
    const float* lws  = (const float*)d_in[6];   // log_wght_s [8192]
    float* out = (float*)d_out;

    constexpr size_t MK = (size_t)8192 * 2048;
    _Float16* xq = (_Float16*)d_ws;
    _Float16* wq = (_Float16*)((char*)d_ws + MK * sizeof(_Float16));

    quant_kernel<<<16384, 256, 0, stream>>>(x, las, laq, ab, w, lws, xq, wq);
    gemm_kernel<<<1024, 512, 0, stream>>>(xq, wq, bias, out);
}